// Round 16
// baseline (177.188 us; speedup 1.0000x reference)
//
#include <hip/hip_runtime.h>
#include <hip/hip_fp16.h>

// out[b, m, r] = x[b, ind[r,m]] * filters[r, ind[r,m]]
// rem = m*512+r; out flat = b*65536 + rem.
//
// map16 = persistent 4-row blocks (grid=256 = exactly 1 block/CU, single
// dispatch round) with read/write overlap inside the block:
//   ALL 16 x-loads for row k+1 are issued BEFORE row k's first store.
//   vmcnt retires in order, so waits on those loads (at the cvt after
//   compute) never drain stores; the HBM read of row k+1 runs concurrently
//   with row k's store stream. Stage phase shrinks to cvt + ds_write.
//   (map8 failed because its prefetch was issued AFTER the stores ->
//   every wait transitively drained the store queue.)
// pk streamed 2-deep as in map14; re-armed oldest-first each round.

constexpr int D_ROW = 128;
constexpr int D_COL = 512;
constexpr int D_ALL = D_ROW * D_COL;   // 65536
constexpr int BATCH = 1024;

// pk[m*512+r] = (fp16bits(filters[r, ind[r,m]]) << 16) | ind[r,m]
__global__ void __launch_bounds__(256)
build_pk(const float* __restrict__ filters,
         const int*   __restrict__ ind,
         unsigned* __restrict__ pk) {
    int t = blockIdx.x * 256 + threadIdx.x;
    if (t >= D_ALL) return;
    int m = t >> 9, r = t & 511;
    int idx = ind[r * D_ROW + m];
    __half hw = __float2half_rn(filters[(size_t)r * D_ALL + idx]);
    pk[t] = ((unsigned)__half_as_ushort(hw) << 16) | (unsigned)idx;
}

__device__ __forceinline__ float map_one(const __half* xs, unsigned p) {
    return __half2float(xs[p & 0xffffu]) *
           __half2float(__ushort_as_half((unsigned short)(p >> 16)));
}
__device__ __forceinline__ unsigned h2bits(float a, float b) {
    __half2 h = __floats2half2_rn(a, b);
    return *reinterpret_cast<unsigned*>(&h);
}
__device__ __forceinline__ void lds_barrier() {
    asm volatile("s_waitcnt lgkmcnt(0)" ::: "memory");
    __builtin_amdgcn_s_barrier();
}

__global__ void __launch_bounds__(1024, 4)
map16(const float* __restrict__ x,
      const uint4* __restrict__ pk4,    // pk4[j*1024 + t]
      float* __restrict__ out) {
    __shared__ __half xs[D_ALL];        // 128 KB: current row as fp16
    const int t = threadIdx.x;          // 0..1023
    const int row0 = blockIdx.x * 4;    // 4 rows per persistent block

    float4 f[16];                       // in-flight next-row loads (64 VGPR)
    uint4  u[8];                        // converted fp16 row (32 VGPR)

    // pk pipeline pre-arm: oldest in the vmcnt queue.
    uint4 pA = pk4[t];
    uint4 pB = pk4[1024 + t];
    __builtin_amdgcn_sched_barrier(0);

    // ---- prologue: stage row0 (issue all -> cvt -> ds_write) ----
    {
        const float4* src = reinterpret_cast<const float4*>(x + ((size_t)row0 << 16));
        #pragma unroll
        for (int i = 0; i < 8; ++i) {
            f[2 * i]     = src[i * 2048 + t * 2];
            f[2 * i + 1] = src[i * 2048 + t * 2 + 1];
        }
    }
    __builtin_amdgcn_sched_barrier(0);
    #pragma unroll
    for (int i = 0; i < 8; ++i) {
        u[i].x = h2bits(f[2 * i].x,     f[2 * i].y);
        u[i].y = h2bits(f[2 * i].z,     f[2 * i].w);
        u[i].z = h2bits(f[2 * i + 1].x, f[2 * i + 1].y);
        u[i].w = h2bits(f[2 * i + 1].z, f[2 * i + 1].w);
    }
    #pragma unroll
    for (int i = 0; i < 8; ++i)
        *reinterpret_cast<uint4*>(xs + (size_t)(i * 2048 + t * 2) * 4) = u[i];
    __builtin_amdgcn_sched_barrier(0);
    // issue row1 loads BEFORE any compute stores (older than all stores)
    {
        const float4* src = reinterpret_cast<const float4*>(
            x + ((size_t)(row0 + 1) << 16));
        #pragma unroll
        for (int i = 0; i < 8; ++i) {
            f[2 * i]     = src[i * 2048 + t * 2];
            f[2 * i + 1] = src[i * 2048 + t * 2 + 1];
        }
    }
    __builtin_amdgcn_sched_barrier(0);
    lds_barrier();

    #pragma unroll
    for (int k = 0; k < 4; ++k) {
        // ---- compute row k: LDS gathers + streaming stores; pk 2-deep ----
        float* ob = out + ((size_t)(row0 + k) << 16);
        #pragma unroll
        for (int j = 0; j < 16; ++j) {
            uint4 cur = pA;
            pA = pB;
            if (j + 2 < 16) pB = pk4[(j + 2) * 1024 + t];
            float4 r;
            r.x = map_one(xs, cur.x);
            r.y = map_one(xs, cur.y);
            r.z = map_one(xs, cur.z);
            r.w = map_one(xs, cur.w);
            *reinterpret_cast<float4*>(ob + j * 4096 + t * 4) = r;
        }
        if (k < 3) {
            __builtin_amdgcn_sched_barrier(0);
            // cvt row k+1: its loads are OLDER than this round's stores ->
            // the vmcnt waits here complete without draining the stores.
            #pragma unroll
            for (int i = 0; i < 8; ++i) {
                u[i].x = h2bits(f[2 * i].x,     f[2 * i].y);
                u[i].y = h2bits(f[2 * i].z,     f[2 * i].w);
                u[i].z = h2bits(f[2 * i + 1].x, f[2 * i + 1].y);
                u[i].w = h2bits(f[2 * i + 1].z, f[2 * i + 1].w);
            }
            // re-arm pk (older than the row k+2 loads below)
            pA = pk4[t];
            pB = pk4[1024 + t];
            __builtin_amdgcn_sched_barrier(0);
            // issue row k+2 loads now (overlap: other waves still gathering)
            if (k < 2) {
                const float4* src = reinterpret_cast<const float4*>(
                    x + ((size_t)(row0 + k + 2) << 16));
                #pragma unroll
                for (int i = 0; i < 8; ++i) {
                    f[2 * i]     = src[i * 2048 + t * 2];
                    f[2 * i + 1] = src[i * 2048 + t * 2 + 1];
                }
            }
            __builtin_amdgcn_sched_barrier(0);
            lds_barrier();          // all gathers of row k complete
            #pragma unroll
            for (int i = 0; i < 8; ++i)
                *reinterpret_cast<uint4*>(xs + (size_t)(i * 2048 + t * 2) * 4) = u[i];
            lds_barrier();          // xs(k+1) visible to all waves
        }
    }
}

// ---------------- fallback: direct gather (correct, slow) ----------------
__global__ void __launch_bounds__(256)
map_kernel_nows(const float* __restrict__ x,
                const float* __restrict__ filters,
                const int*   __restrict__ ind,
                float*       __restrict__ out) {
    size_t o = (size_t)blockIdx.x * 256 + threadIdx.x;
    if (o >= (size_t)BATCH * D_ALL) return;
    unsigned b = (unsigned)(o >> 16);
    unsigned rem = (unsigned)(o & 65535u);
    unsigned m = rem >> 9, r = rem & 511u;
    int idx = ind[r * D_ROW + m];
    out[o] = x[((size_t)b << 16) + idx] * filters[(size_t)r * D_ALL + idx];
}

extern "C" void kernel_launch(void* const* d_in, const int* in_sizes, int n_in,
                              void* d_out, int out_size, void* d_ws, size_t ws_size,
                              hipStream_t stream) {
    const float* x       = (const float*)d_in[0];
    const float* filters = (const float*)d_in[1];
    const int*   ind     = (const int*)d_in[2];
    float*       out     = (float*)d_out;

    const size_t need = (size_t)D_ALL * sizeof(unsigned);   // 256 KB
    if (ws_size >= need) {
        unsigned* pk = (unsigned*)d_ws;
        build_pk<<<D_ALL / 256, 256, 0, stream>>>(filters, ind, pk);
        map16<<<BATCH / 4, 1024, 0, stream>>>(
            x, reinterpret_cast<const uint4*>(pk), out);
    } else {
        map_kernel_nows<<<(BATCH * (size_t)D_ALL) / 256, 256, 0, stream>>>(
            x, filters, ind, out);
    }
}